// Round 11
// baseline (148.414 us; speedup 1.0000x reference)
//
#include <hip/hip_runtime.h>

#define B_ 128
#define O_ 1024
#define I_ 1024
#define NCHUNK 128
#define CI (I_ / NCHUNK)     // 8 i-values per wave
#define WPB 4                // waves per block
#define BPW 2                // batches per wave (b-pairing: row loaded once, used twice)
#define TT_BYTES ((size_t)O_ * I_ * sizeof(float))

#define LOG2E_F  1.4426950408889634f
#define LN2_F    0.6931471805599453f
#define LN2SQ_F  0.4804530139182014f          // ln2^2
#define EPSC_F   (1e-7f * LN2SQ_F)            // eps * ln2^2

typedef float v2f __attribute__((ext_vector_type(2)));

__device__ __forceinline__ float fast_rsq(float x)  { return __builtin_amdgcn_rsqf(x); }
__device__ __forceinline__ float fast_exp2(float x) { return __builtin_amdgcn_exp2f(x); }
__device__ __forceinline__ float fast_rcp(float x)  { return __builtin_amdgcn_rcpf(x); }

__device__ __forceinline__ float rfl(float x) {
    return __builtin_bit_cast(float,
        __builtin_amdgcn_readfirstlane(__builtin_bit_cast(int, x)));
}

template <int CTRL>
__device__ __forceinline__ float dpp_add(float v) {
    int x = __builtin_amdgcn_update_dpp(0, __builtin_bit_cast(int, v),
                                        CTRL, 0xf, 0xf, true);
    return v + __builtin_bit_cast(float, x);
}
// 64-lane sum -> SGPR-uniform
__device__ __forceinline__ float wave_sum_uniform(float v) {
    v = dpp_add<0xB1>(v);   // quad_perm [1,0,3,2]
    v = dpp_add<0x4E>(v);   // quad_perm [2,3,0,1]
    v = dpp_add<0x141>(v);  // row_half_mirror
    v = dpp_add<0x140>(v);  // row_mirror
    v = dpp_add<0x142>(v);  // row_bcast15
    v = dpp_add<0x143>(v);  // row_bcast31
    return __builtin_bit_cast(float,
        __builtin_amdgcn_readlane(__builtin_bit_cast(int, v), 63));
}

// ---------------------------------------------------------------------------
// Kernel 1 (exact): Tt2[i*O+o] = T[o,i]^2 transposed; per-i min of T^2 via
// bitwise atomicMin (float bits monotone for >=0); d_out zeroing folded in.
// ---------------------------------------------------------------------------
__global__ __launch_bounds__(256) void build_T2_kernel(
    const float* __restrict__ ix, const float* __restrict__ iy,
    const float* __restrict__ ox, const float* __restrict__ oy,
    const float* __restrict__ la, const float* __restrict__ lm,
    float* __restrict__ Tt2, unsigned* __restrict__ minbits,
    float* __restrict__ out_zero)
{
    __shared__ float tile[32][33];
    __shared__ unsigned mloc[32];
    const int i0 = blockIdx.x * 32;
    const int o0 = blockIdx.y * 32;
    const int tx = threadIdx.x;      // 0..31
    const int ty = threadIdx.y;      // 0..7
    const int t  = ty * 32 + tx;     // 0..255

    if (t < 32) mloc[t] = 0xFFFFFFFFu;

    const int bid = blockIdx.y * gridDim.x + blockIdx.x;   // 0..1023
    if (t < 128) out_zero[bid * 128 + t] = 0.0f;

#pragma unroll
    for (int r = 0; r < 32; r += 8) {
        const int o = o0 + ty + r;
        const int i = i0 + tx;
        const int idx = o * I_ + i;
        const float tt = fmaf(ix[idx] * fast_rcp(iy[idx]) + la[idx],
                              1.0f + lm[idx],
                              -(ox[idx] * fast_rcp(oy[idx])));
        tile[ty + r][tx] = tt * tt;
    }
    __syncthreads();
#pragma unroll
    for (int r = 0; r < 32; r += 8) {
        const int i = i0 + ty + r;
        const int o = o0 + tx;
        Tt2[i * O_ + o] = tile[tx][ty + r];
    }
    const int il = t & 31;
    const int g  = t >> 5;
    float mn = fminf(fminf(tile[4 * g + 0][il], tile[4 * g + 1][il]),
                     fminf(tile[4 * g + 2][il], tile[4 * g + 3][il]));
    atomicMin(&mloc[il], __builtin_bit_cast(unsigned, mn));
    __syncthreads();
    if (t < 32) atomicMin(&minbits[i0 + t], mloc[t]);
}

// ---------------------------------------------------------------------------
// Kernel 2 (b-paired): wave owns 8 i's x TWO b's; lane owns 16 o's. Each Tt2
// row is loaded ONCE and consumed by both b-bodies (halves L2 read traffic:
// 512->256 MB), and b1's transcendental block overlaps b0's serial DPP
// z-reduce (in-wave ILP across the reduction). e0 uses fresh regs (row still
// needed for b1); e1 overwrites the dying row regs. No explicit prefetch —
// protects the register budget (R8 lesson: VGPR 128 => 2 waves/SIMD
// disaster; R9: forced bound => spill catastrophe).
// ---------------------------------------------------------------------------
__global__ __launch_bounds__(256) void aeg_main_kernel(
    const float* __restrict__ data,   // (B, I)
    const float* __restrict__ Tt2,    // (I, O) transposed T^2
    const float* __restrict__ minr2,  // (I) min T^2 (float bits)
    float* __restrict__ out)          // (B, O), zeroed by build_T2
{
    __shared__ float red[WPB][O_];    // 16 KB

    const int w    = threadIdx.x >> 6;
    const int lane = threadIdx.x & 63;
    const int chunk = blockIdx.x * WPB + w;     // 0..127
    const int b0    = blockIdx.y * BPW;         // 0,2,..126
    const int b1    = b0 + 1;

    const float4* rowbase = (const float4*)(Tt2 + (size_t)chunk * CI * O_);

    // ---- prologue: wave-uniform per-i values for BOTH b's into SGPRs ----
    const float4* d04 = (const float4*)(data + b0 * I_ + chunk * CI);
    const float4* d14 = (const float4*)(data + b1 * I_ + chunk * CI);
    const float4* mr4 = (const float4*)(minr2 + chunk * CI);
    float sdv0[CI], ss20[CI], sm20[CI];
    float sdv1[CI], ss21[CI], sm21[CI];
#pragma unroll
    for (int k = 0; k < 2; ++k) {                  // CI=8 -> 2 float4 each
        const float4 a0 = d04[k];
        const float4 a1 = d14[k];
        const float4 m  = mr4[k];
        const float a0v[4] = {a0.x, a0.y, a0.z, a0.w};
        const float a1v[4] = {a1.x, a1.y, a1.z, a1.w};
        const float mv[4]  = {m.x,  m.y,  m.z,  m.w};
#pragma unroll
        for (int j = 0; j < 4; ++j) {
            const int idx = 4 * k + j;
            {
                const float dv  = a0v[j];
                const float sig = fast_rcp(1.0f + fast_exp2(-dv * LOG2E_F));
                const float sc  = sig * LN2_F;
                const float s2  = sc * sc;
                sdv0[idx] = rfl(dv);
                ss20[idx] = rfl(s2);
                sm20[idx] = rfl(fast_rsq(fmaf(mv[j], s2, EPSC_F)));
            }
            {
                const float dv  = a1v[j];
                const float sig = fast_rcp(1.0f + fast_exp2(-dv * LOG2E_F));
                const float sc  = sig * LN2_F;
                const float s2  = sc * sc;
                sdv1[idx] = rfl(dv);
                ss21[idx] = rfl(s2);
                sm21[idx] = rfl(fast_rsq(fmaf(mv[j], s2, EPSC_F)));
            }
        }
    }

    v2f acc0[8], acc1[8];
#pragma unroll
    for (int j = 0; j < 8; ++j) { acc0[j] = (v2f)0.0f; acc1[j] = (v2f)0.0f; }

#pragma unroll
    for (int ii = 0; ii < CI; ++ii) {
        const float4* rowp = rowbase + (size_t)ii * (O_ / 4);
        float4 r[4];
#pragma unroll
        for (int k = 0; k < 4; ++k) r[k] = rowp[lane + 64 * k];

        // ---- b0: e into FRESH regs (row still needed for b1) ----
        const v2f s2v0 = {ss20[ii], ss20[ii]};
        const v2f m2v0 = {sm20[ii], sm20[ii]};
        const v2f epv  = {EPSC_F, EPSC_F};
        float4 e0[4];
        v2f z0a = (v2f)0.0f, z0b = (v2f)0.0f;
#pragma unroll
        for (int k = 0; k < 4; ++k) {
            const v2f a = {r[k].x, r[k].y};
            const v2f c = {r[k].z, r[k].w};
            const v2f q0 = a * s2v0 + epv;
            const v2f q1 = c * s2v0 + epv;
            v2f t0, t1;
            t0.x = fast_rsq(q0.x); t0.y = fast_rsq(q0.y);
            t1.x = fast_rsq(q1.x); t1.y = fast_rsq(q1.y);
            t0 -= m2v0;
            t1 -= m2v0;
            e0[k].x = fast_exp2(t0.x); e0[k].y = fast_exp2(t0.y);
            e0[k].z = fast_exp2(t1.x); e0[k].w = fast_exp2(t1.y);
            z0a += (v2f){e0[k].x, e0[k].y};
            z0b += (v2f){e0[k].z, e0[k].w};
        }
        const v2f z0v = z0a + z0b;
        const float zt0 = wave_sum_uniform(z0v.x + z0v.y);

        // ---- b1: e IN-PLACE over the dying row regs (overlaps z0 chain) ----
        const v2f s2v1 = {ss21[ii], ss21[ii]};
        const v2f m2v1 = {sm21[ii], sm21[ii]};
        v2f z1a = (v2f)0.0f, z1b = (v2f)0.0f;
#pragma unroll
        for (int k = 0; k < 4; ++k) {
            const v2f a = {r[k].x, r[k].y};
            const v2f c = {r[k].z, r[k].w};
            const v2f q0 = a * s2v1 + epv;
            const v2f q1 = c * s2v1 + epv;
            v2f t0, t1;
            t0.x = fast_rsq(q0.x); t0.y = fast_rsq(q0.y);
            t1.x = fast_rsq(q1.x); t1.y = fast_rsq(q1.y);
            t0 -= m2v1;
            t1 -= m2v1;
            r[k].x = fast_exp2(t0.x); r[k].y = fast_exp2(t0.y);
            r[k].z = fast_exp2(t1.x); r[k].w = fast_exp2(t1.y);
            z1a += (v2f){r[k].x, r[k].y};
            z1b += (v2f){r[k].z, r[k].w};
        }
        const float sc0 = sdv0[ii] * fast_rcp(zt0);
        const v2f sc0v = {sc0, sc0};
#pragma unroll
        for (int k = 0; k < 4; ++k) {
            acc0[2 * k]     = (v2f){e0[k].x, e0[k].y} * sc0v + acc0[2 * k];
            acc0[2 * k + 1] = (v2f){e0[k].z, e0[k].w} * sc0v + acc0[2 * k + 1];
        }
        const v2f z1v = z1a + z1b;
        const float zt1 = wave_sum_uniform(z1v.x + z1v.y);
        const float sc1 = sdv1[ii] * fast_rcp(zt1);
        const v2f sc1v = {sc1, sc1};
#pragma unroll
        for (int k = 0; k < 4; ++k) {
            acc1[2 * k]     = (v2f){r[k].x, r[k].y} * sc1v + acc1[2 * k];
            acc1[2 * k + 1] = (v2f){r[k].z, r[k].w} * sc1v + acc1[2 * k + 1];
        }
    }

    // ---- epilogue: cross-wave LDS reduce + atomics, b0 then b1 ----
    const int t = threadIdx.x;
#pragma unroll
    for (int k = 0; k < 4; ++k) {
        float4 v;
        v.x = acc0[2 * k].x;     v.y = acc0[2 * k].y;
        v.z = acc0[2 * k + 1].x; v.w = acc0[2 * k + 1].y;
        ((float4*)&red[w][256 * k])[lane] = v;
    }
    __syncthreads();
    {
        float4 v = ((const float4*)red[0])[t];
#pragma unroll
        for (int ww = 1; ww < WPB; ++ww) {
            const float4 u = ((const float4*)red[ww])[t];
            v.x += u.x; v.y += u.y; v.z += u.z; v.w += u.w;
        }
        float* ob = out + b0 * O_ + 4 * t;
        atomicAdd(&ob[0], v.x);
        atomicAdd(&ob[1], v.y);
        atomicAdd(&ob[2], v.z);
        atomicAdd(&ob[3], v.w);
    }
    __syncthreads();
#pragma unroll
    for (int k = 0; k < 4; ++k) {
        float4 v;
        v.x = acc1[2 * k].x;     v.y = acc1[2 * k].y;
        v.z = acc1[2 * k + 1].x; v.w = acc1[2 * k + 1].y;
        ((float4*)&red[w][256 * k])[lane] = v;
    }
    __syncthreads();
    {
        float4 v = ((const float4*)red[0])[t];
#pragma unroll
        for (int ww = 1; ww < WPB; ++ww) {
            const float4 u = ((const float4*)red[ww])[t];
            v.x += u.x; v.y += u.y; v.z += u.z; v.w += u.w;
        }
        float* ob = out + b1 * O_ + 4 * t;
        atomicAdd(&ob[0], v.x);
        atomicAdd(&ob[1], v.y);
        atomicAdd(&ob[2], v.z);
        atomicAdd(&ob[3], v.w);
    }
}

// ---------------------------------------------------------------------------
extern "C" void kernel_launch(void* const* d_in, const int* in_sizes, int n_in,
                              void* d_out, int out_size, void* d_ws, size_t ws_size,
                              hipStream_t stream)
{
    const float* data = (const float*)d_in[0];
    const float* ix   = (const float*)d_in[1];
    const float* iy   = (const float*)d_in[2];
    const float* ox   = (const float*)d_in[3];
    const float* oy   = (const float*)d_in[4];
    const float* la   = (const float*)d_in[5];
    const float* lm   = (const float*)d_in[6];
    float* out  = (float*)d_out;
    float* Tt2  = (float*)d_ws;
    unsigned* minbits = (unsigned*)((char*)d_ws + TT_BYTES);

    (void)hipMemsetAsync(minbits, 0xFF, I_ * sizeof(unsigned), stream);

    build_T2_kernel<<<dim3(I_ / 32, O_ / 32), dim3(32, 8), 0, stream>>>(
        ix, iy, ox, oy, la, lm, Tt2, minbits, out);

    aeg_main_kernel<<<dim3(NCHUNK / WPB, B_ / BPW), 256, 0, stream>>>(
        data, Tt2, (const float*)minbits, out);
}